// Round 16
// baseline (29.393 us; speedup 1.0000x reference)
//
#include <hip/hip_runtime.h>

// MultiHeadRouter: B=2, L=4096, H=16, S=64, D=128
// out (float32): [T*H ones][T*H argmax-as-float][1 loss], T = 8192
//
// R16: 32x32x16 MFMA, swapped operands: P[state][token] = W x X^T.
// C-layout (m74/m101): col=lane&31=token, row=(reg&3)+8*(reg>>2)+4*(lane>>5).
// -> each token's 64 logits live in 2 lanes x 32 regs: argmax/softmax-denom
//    become register-local (31 fmax / 31 adds) + ONE shfl_xor(32).
// In-loop DS-ops drop ~30x vs R15; ds_reads and MFMAs halve per token.
// Counts: block LDS histogram (1 ds_atomic/tile). Score-sums: DPP row_shr
// reduction (VALU pipe) + per-block atomic. Bias folded into acc init.
// f16 2-split (hh+hl+lh) unchanged; argmax-on-logits == argmax-on-score.

#define TOKENS  8192
#define NHEAD   16
#define NSTATE  64
#define DDIM    128
#define TH      (TOKENS * NHEAD)

// d_ws layout
#define WFRAG_BYTES (1u << 19)                  // 512 KB: 16 heads x 32 KB
#define BFRAG_OFF   WFRAG_BYTES                 // 4 KB bias frags [h][hi][32]
#define BFRAG_BYTES 4096
#define REP_OFF     (WFRAG_BYTES + BFRAG_BYTES) // repf[8][1024], repc[8][1024]
#define REP_BYTES   65536
#define IDX_OFF     (REP_OFF + REP_BYTES)       // 512 KB idx_scr[16][8192]

typedef _Float16 half8  __attribute__((ext_vector_type(8)));
typedef float    f32x4  __attribute__((ext_vector_type(4)));
typedef float    f32x16 __attribute__((ext_vector_type(16)));

#define GLOAD_LDS16(gsrc, ldst)                                           \
    __builtin_amdgcn_global_load_lds(                                     \
        (const __attribute__((address_space(1))) void*)(gsrc),            \
        (__attribute__((address_space(3))) void*)(ldst), 16, 0, 0)

__device__ __forceinline__ void split8(const f32x4 v0, const f32x4 v1,
                                       half8& hh, half8& ll) {
    #pragma unroll
    for (int j = 0; j < 4; ++j) {
        _Float16 h0 = (_Float16)v0[j];
        hh[j]     = h0;  ll[j]     = (_Float16)(v0[j] - (float)h0);
        _Float16 h1 = (_Float16)v1[j];
        hh[4 + j] = h1;  ll[4 + j] = (_Float16)(v1[j] - (float)h1);
    }
}

// sum over each 32-lane half via DPP (VALU pipe, no DS). Valid in lanes 31/63.
__device__ __forceinline__ float dpp_sum32(float v) {
    float t;
    t = __int_as_float(__builtin_amdgcn_update_dpp(0, __float_as_int(v), 0x111, 0xf, 0xf, true)); v += t; // row_shr:1
    t = __int_as_float(__builtin_amdgcn_update_dpp(0, __float_as_int(v), 0x112, 0xf, 0xf, true)); v += t; // row_shr:2
    t = __int_as_float(__builtin_amdgcn_update_dpp(0, __float_as_int(v), 0x114, 0xf, 0xf, true)); v += t; // row_shr:4
    t = __int_as_float(__builtin_amdgcn_update_dpp(0, __float_as_int(v), 0x118, 0xf, 0xf, true)); v += t; // row_shr:8
    t = __int_as_float(__builtin_amdgcn_update_dpp(0, __float_as_int(v), 0x142, 0xf, 0xf, true)); v += t; // row_bcast:15
    return v;
}

// One-shot: W -> 32x32-operand f16 hi/lo fragment planes; bias -> reg-order
// frags; zero the atomic replicas.
// Frag f = ks*4 + half*2 + plane (ks<8, half = state-tile). Lane l holds
// W[s = 32*half + (l&31)][k = ks*16 + (l>>5)*8 .. +8].
__global__ __launch_bounds__(256)
void prep_w(const float* __restrict__ w, const float* __restrict__ bias,
            half8* __restrict__ wfrag, float* __restrict__ bfrag,
            float* __restrict__ rep)
{
    const int t = blockIdx.x * 256 + threadIdx.x;   // 16384 threads
    rep[t] = 0.0f;
    const int lane  = t & 63;
    const int half_ = (t >> 6) & 1;
    const int ks    = (t >> 7) & 7;
    const int h     = t >> 10;
    const int s     = half_ * 32 + (lane & 31);
    const int k0    = ks * 16 + (lane >> 5) * 8;
    const float* src = w + (size_t)(h * NSTATE + s) * DDIM + k0;
    f32x4 v0 = *reinterpret_cast<const f32x4*>(src);
    f32x4 v1 = *reinterpret_cast<const f32x4*>(src + 4);
    half8 hv, lv;
    split8(v0, v1, hv, lv);
    const size_t fb = (size_t)h * 2048 + (size_t)((ks * 4 + half_ * 2)) * 64;
    wfrag[fb + lane]      = hv;
    wfrag[fb + 64 + lane] = lv;

    if (t < 1024) {   // bias frags: bfrag[h][hi][j], j = tau*16 + r
        const int h2 = t >> 6, hi2 = (t >> 5) & 1, j = t & 31;
        const int tau = j >> 4, r = j & 15;
        const int s2 = (r & 3) + ((r >> 2) << 3) + (hi2 << 2) + (tau << 5);
        bfrag[t] = bias[h2 * NSTATE + s2];
    }
}

__global__ __launch_bounds__(256)
void router_mfma(const float* __restrict__ x,      // [T,H,D]
                 const half8* __restrict__ wfrag,
                 const float* __restrict__ bfrag,
                 float* __restrict__ idx_scr,      // [H][T]
                 float* __restrict__ repf,         // [8][1024]
                 float* __restrict__ repc)         // [8][1024]
{
    __shared__ __align__(16) unsigned char smem[32768];   // W frag planes
    __shared__ unsigned int hist[64];                     // block count hist
    __shared__ __align__(16) float ssums[4][64];          // per-wave score sums

    const int blk  = blockIdx.x;        // 1024: h = low 4 bits (bi-major)
    const int h    = blk & 15;
    const int grp  = blk >> 4;          // 64 groups x 128 tokens
    const int tid  = threadIdx.x;
    const int wave = __builtin_amdgcn_readfirstlane(tid >> 6);
    const int lane = tid & 63;
    const int tk   = lane & 31;         // token within tile (C col)
    const int hi   = lane >> 5;
    const int tokb = grp * 128 + wave * 32;

    // ---- stage W planes: 32 KB linear gload_lds ----
    {
        const char* wsrc = (const char*)wfrag + (size_t)h * 32768;
        #pragma unroll
        for (int i = 0; i < 8; ++i) {
            const int off = (i * 256 + tid) * 16;
            GLOAD_LDS16(wsrc + off, smem + off);
        }
    }
    if (tid < 64) hist[tid] = 0;

    // acc init = bias (C = bias broadcast across token columns)
    const float* bf = bfrag + ((h << 1) | hi) * 32;
    f32x16 acc0, acc1;
    #pragma unroll
    for (int r = 0; r < 16; ++r) { acc0[r] = bf[r]; acc1[r] = bf[16 + r]; }

    const float* xrow = x + (size_t)(tokb + tk) * (NHEAD * DDIM) + h * DDIM + hi * 8;

    __syncthreads();   // W planes + hist ready

    // ---- 8 k-steps x (2 state-halves x 3 split-terms) MFMA ----
    #pragma unroll
    for (int ks = 0; ks < 8; ++ks) {
        half8 wh0 = *reinterpret_cast<const half8*>(smem + (ks * 4 + 0) * 1024 + lane * 16);
        half8 wl0 = *reinterpret_cast<const half8*>(smem + (ks * 4 + 1) * 1024 + lane * 16);
        half8 wh1 = *reinterpret_cast<const half8*>(smem + (ks * 4 + 2) * 1024 + lane * 16);
        half8 wl1 = *reinterpret_cast<const half8*>(smem + (ks * 4 + 3) * 1024 + lane * 16);
        f32x4 g0 = *reinterpret_cast<const f32x4*>(xrow + ks * 16);
        f32x4 g1 = *reinterpret_cast<const f32x4*>(xrow + ks * 16 + 4);
        half8 xh, xl;
        split8(g0, g1, xh, xl);
        acc0 = __builtin_amdgcn_mfma_f32_32x32x16_f16(wh0, xh, acc0, 0, 0, 0);
        acc0 = __builtin_amdgcn_mfma_f32_32x32x16_f16(wh0, xl, acc0, 0, 0, 0);
        acc0 = __builtin_amdgcn_mfma_f32_32x32x16_f16(wl0, xh, acc0, 0, 0, 0);
        acc1 = __builtin_amdgcn_mfma_f32_32x32x16_f16(wh1, xh, acc1, 0, 0, 0);
        acc1 = __builtin_amdgcn_mfma_f32_32x32x16_f16(wh1, xl, acc1, 0, 0, 0);
        acc1 = __builtin_amdgcn_mfma_f32_32x32x16_f16(wl1, xh, acc1, 0, 0, 0);
    }

    // ---- epilogue: lane holds 32 logits of token tk (states interleaved) ----
    // local max (order-free), then descending-state select -> lowest-s argmax
    float mx = acc1[15];
    #pragma unroll
    for (int r = 14; r >= 0; --r) mx = fmaxf(mx, acc1[r]);
    #pragma unroll
    for (int r = 15; r >= 0; --r) mx = fmaxf(mx, acc0[r]);

    int idx = 0;
    #pragma unroll
    for (int r = 15; r >= 0; --r) {   // tau=1 states (32..63), s desc in r
        const int s = 32 + (r & 3) + ((r >> 2) << 3) + (hi << 2);
        idx = (acc1[r] == mx) ? s : idx;
    }
    #pragma unroll
    for (int r = 15; r >= 0; --r) {   // tau=0 states (0..31)
        const int s = (r & 3) + ((r >> 2) << 3) + (hi << 2);
        idx = (acc0[r] == mx) ? s : idx;
    }
    // merge with partner lane (other 32 states of the same token)
    {
        const float omx  = __shfl_xor(mx, 32);
        const int   oidx = __shfl_xor(idx, 32);
        if (omx > mx || (omx == mx && oidx < idx)) { mx = omx; idx = oidx; }
    }

    // softmax scores (no max-subtract: |logit| <= ~65 << 88); loss-only
    float sm = 0.f;
    #pragma unroll
    for (int r = 0; r < 16; ++r) { acc0[r] = __expf(acc0[r]); sm += acc0[r]; }
    #pragma unroll
    for (int r = 0; r < 16; ++r) { acc1[r] = __expf(acc1[r]); sm += acc1[r]; }
    sm += __shfl_xor(sm, 32);
    const float rinv = __builtin_amdgcn_rcpf(sm);

    // per-state score sums across the 32 token-lanes (DPP, VALU pipe)
    #pragma unroll
    for (int r = 0; r < 16; ++r) {
        acc0[r] = dpp_sum32(acc0[r] * rinv);
        acc1[r] = dpp_sum32(acc1[r] * rinv);
    }
    if ((lane & 31) == 31) {          // lanes 31 (hi=0) / 63 (hi=1)
        #pragma unroll
        for (int g = 0; g < 4; ++g) { // r=4g..4g+3 -> states 8g+4hi..+3
            f32x4 p0, p1;
            #pragma unroll
            for (int i = 0; i < 4; ++i) { p0[i] = acc0[g * 4 + i]; p1[i] = acc1[g * 4 + i]; }
            *reinterpret_cast<f32x4*>(&ssums[wave][(g << 3) + (hi << 2)])      = p0;
            *reinterpret_cast<f32x4*>(&ssums[wave][32 + (g << 3) + (hi << 2)]) = p1;
        }
    }

    if (hi == 0) {
        atomicAdd(&hist[idx], 1u);                                     // counts
        idx_scr[(size_t)h * TOKENS + tokb + tk] = (float)idx;          // coalesced
    }

    __syncthreads();   // all waves' ssums + hist complete
    if (wave == 0) {
        const float sv = ssums[0][lane] + ssums[1][lane] + ssums[2][lane] + ssums[3][lane];
        const float cv = (float)hist[lane];
        const int rep = blk & 7;
        atomicAdd(repf + rep * 1024 + h * 64 + lane, sv);
        atomicAdd(repc + rep * 1024 + h * 64 + lane, cv);
    }
}

// finale: blocks 0-31 transpose idx_scr->out + ones plane; block 32 = loss.
__global__ __launch_bounds__(256)
void finale(const float* __restrict__ idx_scr,
            const float* __restrict__ repf,
            const float* __restrict__ repc,
            float* __restrict__ out)
{
    const int b   = blockIdx.x;
    const int tid = threadIdx.x;

    if (b < 32) {
        __shared__ float tl[256 * 17];      // padded: conflict-free transpose
        #pragma unroll
        for (int hh = 0; hh < 16; ++hh)
            tl[tid * 17 + hh] = idx_scr[(size_t)hh * TOKENS + b * 256 + tid];
        __syncthreads();
        #pragma unroll
        for (int k = 0; k < 16; ++k) {
            const int i = k * 256 + tid;    // 4096 outputs per block
            out[(size_t)TH + (size_t)b * 4096 + i] = tl[(i >> 4) * 17 + (i & 15)];
            out[(size_t)b * 4096 + i] = 1.0f;
        }
    } else {
        float part = 0.0f;
        for (int j = tid; j < NHEAD * NSTATE; j += 256) {
            float cf = 0.f, cc = 0.f;
            #pragma unroll
            for (int r = 0; r < 8; ++r) {
                cf += repf[r * 1024 + j];
                cc += repc[r * 1024 + j];
            }
            part += cf * cc;
        }
        #pragma unroll
        for (int d = 1; d <= 32; d <<= 1)
            part += __shfl_xor(part, d);
        __shared__ float red[4];
        const int wv = tid >> 6, lane = tid & 63;
        if (lane == 0) red[wv] = part;
        __syncthreads();
        if (tid == 0) {
            const float tot = red[0] + red[1] + red[2] + red[3];
            const float T = (float)TOKENS;
            out[2 * (size_t)TH] = tot * ((float)NSTATE / (T * T));
        }
    }
}

extern "C" void kernel_launch(void* const* d_in, const int* in_sizes, int n_in,
                              void* d_out, int out_size, void* d_ws, size_t ws_size,
                              hipStream_t stream)
{
    const float* x    = (const float*)d_in[0];
    const float* w    = (const float*)d_in[1];
    const float* bias = (const float*)d_in[2];
    float* out = (float*)d_out;

    half8* wfrag   = (half8*)d_ws;
    float* bfrag   = (float*)((char*)d_ws + BFRAG_OFF);
    float* rep     = (float*)((char*)d_ws + REP_OFF);
    float* repf    = rep;
    float* repc    = rep + 8192;
    float* idx_scr = (float*)((char*)d_ws + IDX_OFF);

    prep_w<<<dim3(64), dim3(256), 0, stream>>>(w, bias, wfrag, bfrag, rep);
    router_mfma<<<dim3(1024), dim3(256), 0, stream>>>(x, wfrag, bfrag,
                                                      idx_scr, repf, repc);
    finale<<<dim3(33), dim3(256), 0, stream>>>(idx_scr, repf, repc, out);
}